// Round 5
// baseline (62.137 us; speedup 1.0000x reference)
//
#include <hip/hip_runtime.h>

static constexpr int DATA_BITS  = 48;
static constexpr int SHIFT_BITS = 6;
static constexpr int THREADS    = 256;   // 4 waves; each wave owns 64 rows
static constexpr int ROWS       = 256;
static constexpr int ROW_DW     = 13;    // LDS data row stride in dwords (52 B, gcd(13,32)=1)
static constexpr int RES_DW     = 3;     // LDS result row stride in dwords (12 B)

typedef float vf4 __attribute__((ext_vector_type(4)));
typedef float vf2 __attribute__((ext_vector_type(2)));

// system-scope non-temporal store: bypass L1/L2/MALL allocation so output
// writes don't evict X from the 256MB Infinity Cache between graph replays.
__device__ __forceinline__ void store_nt_x4(float* p, vf4 v) {
    asm volatile("global_store_dwordx4 %0, %1, off sc0 sc1 nt"
                 :: "v"(p), "v"(v) : "memory");
}
__device__ __forceinline__ void store_nt_x1(float* p, float v) {
    asm volatile("global_store_dword %0, %1, off sc0 sc1 nt"
                 :: "v"(p), "v"(v) : "memory");
}

__global__ __launch_bounds__(256) void barrel48_kernel(
    const float* __restrict__ X, const float* __restrict__ shift,
    float* __restrict__ out, int B)
{
    __shared__ unsigned lds_data[ROWS * ROW_DW];  // 13312 B, bits-as-bytes
    __shared__ unsigned lds_res [ROWS * RES_DW];  // 3072 B, packed 48-bit results

    const unsigned tid  = threadIdx.x;
    const unsigned wv   = tid >> 6;               // wave id 0..3
    const unsigned lane = tid & 63;
    const size_t rowbase = (size_t)blockIdx.x * ROWS;

    // ---------- phase 1 (wave-local): coalesced load -> bytes in LDS ----------
    const vf4* xb = reinterpret_cast<const vf4*>(X + rowbase * DATA_BITS);
    #pragma unroll
    for (int j = 0; j < 12; ++j) {
        unsigned f4 = wv * 768u + (unsigned)j * 64u + lane;  // contiguous 1KB per instr
        vf4 f = xb[f4];
        unsigned r = f4 / 12u;                               // row in tile (wave-local)
        unsigned n = f4 % 12u;
        unsigned pk = (unsigned)f.x | ((unsigned)f.y << 8) |
                      ((unsigned)f.z << 16) | ((unsigned)f.w << 24);
        lds_data[r * ROW_DW + n] = pk;
    }
    __builtin_amdgcn_wave_barrier();   // scheduling fence only; wave-synchronous LDS

    // ---------- phase 2 (wave-local): row pack + shift + sticky ----------
    unsigned hi16 = 0, lo32 = 0;
    #pragma unroll
    for (int n = 0; n < 12; ++n) {
        unsigned d = lds_data[tid * ROW_DW + n];             // own wave's slice
        unsigned q = ((d * 0x08040201u) >> 24) & 0xFu;       // 4 byte-bits -> nibble, MSB first
        if (n < 4) hi16 = (hi16 << 4) | q;                   // v bits 47..32
        else       lo32 = (lo32 << 4) | q;                   // v bits 31..0
    }
    unsigned long long v = ((unsigned long long)hi16 << 32) | (unsigned long long)lo32;

    const vf2* sp = reinterpret_cast<const vf2*>(shift + (rowbase + tid) * SHIFT_BITS);
    vf2 s0 = sp[0], s1 = sp[1], s2 = sp[2];
    float sf = s0.x;
    sf = fmaf(sf, 2.0f, s0.y);
    sf = fmaf(sf, 2.0f, s1.x);
    sf = fmaf(sf, 2.0f, s1.y);
    sf = fmaf(sf, 2.0f, s2.x);
    sf = fmaf(sf, 2.0f, s2.y);
    unsigned s = (unsigned)sf;                               // 0..63

    unsigned long long shifted = v >> s;
    unsigned long long dropped = v & ((1ull << s) - 1ull);

    store_nt_x1(out + (size_t)B * DATA_BITS + rowbase + tid,
                dropped ? 1.0f : 0.0f);

    lds_res[tid * RES_DW + 0] = (unsigned)shifted;           // bits 31..0
    lds_res[tid * RES_DW + 1] = (unsigned)(shifted >> 32);   // bits 47..32
    __builtin_amdgcn_wave_barrier();

    // ---------- phase 3 (wave-local): expand + cache-bypass coalesced store ----------
    float* ob = out + rowbase * DATA_BITS;
    #pragma unroll
    for (int j = 0; j < 12; ++j) {
        unsigned f4 = wv * 768u + (unsigned)j * 64u + lane;
        unsigned r = f4 / 12u;                               // wave-local row
        unsigned n = f4 % 12u;
        unsigned d = lds_res[r * RES_DW + (n < 4u ? 1u : 0u)];
        unsigned nib = (d >> ((44u - 4u * n) & 31u)) & 0xFu;
        vf4 o;
        o.x = (float)((nib >> 3) & 1u);
        o.y = (float)((nib >> 2) & 1u);
        o.z = (float)((nib >> 1) & 1u);
        o.w = (float)( nib       & 1u);
        store_nt_x4(ob + (size_t)f4 * 4u, o);                // contiguous 1KB per instr
    }
}

extern "C" void kernel_launch(void* const* d_in, const int* in_sizes, int n_in,
                              void* d_out, int out_size, void* d_ws, size_t ws_size,
                              hipStream_t stream)
{
    const float* X     = (const float*)d_in[0];
    const float* shift = (const float*)d_in[1];
    float* out         = (float*)d_out;
    int B = in_sizes[0] / DATA_BITS;
    int blocks = (B + ROWS - 1) / ROWS;
    barrel48_kernel<<<blocks, THREADS, 0, stream>>>(X, shift, out, B);
}

// Round 6
// 61.895 us; speedup vs baseline: 1.0039x; 1.0039x over previous
//
#include <hip/hip_runtime.h>

static constexpr int DATA_BITS  = 48;
static constexpr int SHIFT_BITS = 6;
static constexpr int THREADS    = 256;   // 4 waves; each wave owns 64 rows
static constexpr int ROWS       = 256;
static constexpr int ROW_DW     = 13;    // LDS data row stride in dwords (52 B, gcd(13,32)=1)
static constexpr int RES_DW     = 3;     // LDS result row stride in dwords (12 B)

typedef float vf4 __attribute__((ext_vector_type(4)));
typedef float vf2 __attribute__((ext_vector_type(2)));

// non-temporal store (evict-first hint), default device scope — no system-scope
// write-through cost. (sc0/sc1 variant measured identical on FETCH/WRITE.)
__device__ __forceinline__ void store_nt_x4(float* p, vf4 v) {
    asm volatile("global_store_dwordx4 %0, %1, off nt"
                 :: "v"(p), "v"(v) : "memory");
}
__device__ __forceinline__ void store_nt_x1(float* p, float v) {
    asm volatile("global_store_dword %0, %1, off nt"
                 :: "v"(p), "v"(v) : "memory");
}

__global__ __launch_bounds__(256) void barrel48_kernel(
    const float* __restrict__ X, const float* __restrict__ shift,
    float* __restrict__ out, int B)
{
    __shared__ unsigned lds_data[ROWS * ROW_DW];  // 13312 B, bits-as-bytes
    __shared__ unsigned lds_res [ROWS * RES_DW];  // 3072 B, packed 48-bit results

    const unsigned tid  = threadIdx.x;
    const unsigned wv   = tid >> 6;               // wave id 0..3
    const unsigned lane = tid & 63;
    const size_t rowbase = (size_t)blockIdx.x * ROWS;

    // ---------- phase 1 (wave-local): coalesced load -> bytes in LDS ----------
    const vf4* xb = reinterpret_cast<const vf4*>(X + rowbase * DATA_BITS);
    #pragma unroll
    for (int j = 0; j < 12; ++j) {
        unsigned f4 = wv * 768u + (unsigned)j * 64u + lane;  // contiguous 1KB per instr
        vf4 f = xb[f4];
        unsigned r = f4 / 12u;                               // row in tile (wave-local)
        unsigned n = f4 % 12u;
        unsigned pk = (unsigned)f.x | ((unsigned)f.y << 8) |
                      ((unsigned)f.z << 16) | ((unsigned)f.w << 24);
        lds_data[r * ROW_DW + n] = pk;
    }
    __builtin_amdgcn_wave_barrier();   // scheduling fence; wave-synchronous LDS

    // ---------- phase 2 (wave-local): row pack + shift + sticky ----------
    unsigned hi16 = 0, lo32 = 0;
    #pragma unroll
    for (int n = 0; n < 12; ++n) {
        unsigned d = lds_data[tid * ROW_DW + n];             // own wave's slice
        unsigned q = ((d * 0x08040201u) >> 24) & 0xFu;       // 4 byte-bits -> nibble, MSB first
        if (n < 4) hi16 = (hi16 << 4) | q;                   // v bits 47..32
        else       lo32 = (lo32 << 4) | q;                   // v bits 31..0
    }
    unsigned long long v = ((unsigned long long)hi16 << 32) | (unsigned long long)lo32;

    const vf2* sp = reinterpret_cast<const vf2*>(shift + (rowbase + tid) * SHIFT_BITS);
    vf2 s0 = sp[0], s1 = sp[1], s2 = sp[2];
    float sf = s0.x;
    sf = fmaf(sf, 2.0f, s0.y);
    sf = fmaf(sf, 2.0f, s1.x);
    sf = fmaf(sf, 2.0f, s1.y);
    sf = fmaf(sf, 2.0f, s2.x);
    sf = fmaf(sf, 2.0f, s2.y);
    unsigned s = (unsigned)sf;                               // 0..63

    unsigned long long shifted = v >> s;
    unsigned long long dropped = v & ((1ull << s) - 1ull);

    // sticky first: overlaps with phase 3 stores
    store_nt_x1(out + (size_t)B * DATA_BITS + rowbase + tid,
                dropped ? 1.0f : 0.0f);

    lds_res[tid * RES_DW + 0] = (unsigned)shifted;           // bits 31..0
    lds_res[tid * RES_DW + 1] = (unsigned)(shifted >> 32);   // bits 47..32
    __builtin_amdgcn_wave_barrier();

    // ---------- phase 3 (wave-local): paired ds_read -> expand -> store ----------
    float* ob = out + rowbase * DATA_BITS;
    #pragma unroll
    for (int j = 0; j < 12; ++j) {
        unsigned f4 = wv * 768u + (unsigned)j * 64u + lane;
        unsigned r = f4 / 12u;                               // wave-local row
        unsigned n = f4 % 12u;
        unsigned d = lds_res[r * RES_DW + (n < 4u ? 1u : 0u)];
        unsigned nib = (d >> ((44u - 4u * n) & 31u)) & 0xFu;
        vf4 o;
        o.x = (float)((nib >> 3) & 1u);
        o.y = (float)((nib >> 2) & 1u);
        o.z = (float)((nib >> 1) & 1u);
        o.w = (float)( nib       & 1u);
        store_nt_x4(ob + (size_t)f4 * 4u, o);                // contiguous 1KB per instr
        __builtin_amdgcn_wave_barrier();   // keep read->store pairs interleaved
    }
}

extern "C" void kernel_launch(void* const* d_in, const int* in_sizes, int n_in,
                              void* d_out, int out_size, void* d_ws, size_t ws_size,
                              hipStream_t stream)
{
    const float* X     = (const float*)d_in[0];
    const float* shift = (const float*)d_in[1];
    float* out         = (float*)d_out;
    int B = in_sizes[0] / DATA_BITS;
    int blocks = (B + ROWS - 1) / ROWS;
    barrel48_kernel<<<blocks, THREADS, 0, stream>>>(X, shift, out, B);
}